// Round 13
// baseline (286.568 us; speedup 1.0000x reference)
//
#include <hip/hip_runtime.h>
#include <stdint.h>

// B=4, T=4096, H=1024, K=256. BT = 16384, E = 2H = 2048.
// ws layout:
//   x_bf   @ 0          : 33,554,432   (dead after GEMM1)
//   wfragA @ 0          : 9,437,184    (built AFTER GEMM1, overwrites x_bf)
//   wfragB @ 9437184    : 9,437,184
//   w_in_bf  @ 33554432 : 4,194,304
//   w_out_bf @ 37748736 : 4,194,304
//   z        @ 41943040 : 67,108,864   (e, bt) bf16
//   catT     @ 109051904: 67,108,864   (bt, 2e) bf16 (written by fused conv)

#define LDS_AS __attribute__((address_space(3)))
#define GLB_AS __attribute__((address_space(1)))

typedef __attribute__((ext_vector_type(8))) short bf16x8;
typedef __attribute__((ext_vector_type(4))) float f32x4;

__device__ __forceinline__ ushort f2bf(float f) {
  uint32_t u = __float_as_uint(f);
  u += 0x7fffu + ((u >> 16) & 1u);   // RNE
  return (ushort)(u >> 16);
}

// ---------------- cast fp32 -> bf16, 4 elems/thread ----------------
__global__ __launch_bounds__(256) void cast_kernel(const float* __restrict__ in,
                                                   ushort* __restrict__ out, int n4) {
  int i = blockIdx.x * 256 + threadIdx.x;
  if (i >= n4) return;
  float4 v = ((const float4*)in)[i];
  ushort4 o;
  o.x = f2bf(v.x); o.y = f2bf(v.y); o.z = f2bf(v.z); o.w = f2bf(v.w);
  ((ushort4*)out)[i] = o;
}

// ---------------- GEMM 256x256, BK=32, 8 waves (r9 best: 75us) ------------
template <int MODE, int INNER_M>  // MODE 0: bf16 out+bias[row]; 1: f32 out+bias[col]
__global__ __launch_bounds__(512, 2) void gemm256(const ushort* __restrict__ A,
                                                  const ushort* __restrict__ Bt,
                                                  const float* __restrict__ bias,
                                                  void* __restrict__ Cout,
                                                  int M, int N, int Kd, int nbx) {
  __shared__ __attribute__((aligned(16))) ushort lds[65536];  // 4 x (A 16KB + B 16KB)
  const int tid = threadIdx.x;
  const int lane = tid & 63, wid = tid >> 6;
  const int nwg = gridDim.x, bid = blockIdx.x;
  const int s = (bid & 7) * (nwg >> 3) + (bid >> 3);   // XCD swizzle (nwg%8==0)
  const int m0 = (INNER_M ? (s % nbx) : (s / nbx)) * 256;
  const int n0 = (INNER_M ? (s / nbx) : (s % nbx)) * 256;
  const int wm = wid >> 2, wn = wid & 3;
  const int lr = lane & 15;
  const int srow = wid * 16 + (lane >> 2);
  const int scol = ((lane & 3) ^ ((lane >> 3) & 3)) << 3;
  const int rc = (((lane >> 4) ^ ((lane >> 1) & 3)) << 3);

  f32x4 acc[8][4] = {};

  auto stageA = [&](int u) {
    const int boff = (u & 3) * 16384;
    const int kb = u * 32;
#pragma unroll
    for (int rr = 0; rr < 2; ++rr) {
      const ushort* gp = A + (size_t)(m0 + rr * 128 + srow) * Kd + kb + scol;
      __builtin_amdgcn_global_load_lds((const GLB_AS void*)gp,
          (LDS_AS void*)(lds + boff + rr * 4096 + wid * 512), 16, 0, 0);
    }
  };
  auto stageB = [&](int u) {
    const int boff = (u & 3) * 16384 + 8192;
    const int kb = u * 32;
#pragma unroll
    for (int rr = 0; rr < 2; ++rr) {
      const ushort* gp = Bt + (size_t)(n0 + rr * 128 + srow) * Kd + kb + scol;
      __builtin_amdgcn_global_load_lds((const GLB_AS void*)gp,
          (LDS_AS void*)(lds + boff + rr * 4096 + wid * 512), 16, 0, 0);
    }
  };

  stageA(0); stageB(0); stageA(1); stageB(1); stageA(2); stageB(2);
  asm volatile("s_waitcnt vmcnt(8)" ::: "memory");
  __builtin_amdgcn_s_barrier();

  const int NT = Kd >> 5;
  const int abase = (wm * 128 + lr) * 32 + rc;
  const int bbase = 8192 + (wn * 64 + lr) * 32 + rc;

  for (int u = 0; u < NT; ++u) {
    const int boff = (u & 3) * 16384;
    const bool st = (u + 3 < NT);
    bf16x8 af[8], bfr[4];
#pragma unroll
    for (int mi = 0; mi < 8; ++mi)
      af[mi] = *(const bf16x8*)&lds[boff + abase + mi * 512];
#pragma unroll
    for (int ni = 0; ni < 4; ++ni)
      bfr[ni] = *(const bf16x8*)&lds[boff + bbase + ni * 512];
    if (st) {
      stageA(u + 3); stageB(u + 3);
      asm volatile("s_waitcnt vmcnt(8)" ::: "memory");
    } else if (u + 2 < NT) {
      asm volatile("s_waitcnt vmcnt(4)" ::: "memory");
    } else if (u + 1 < NT) {
      asm volatile("s_waitcnt vmcnt(0)" ::: "memory");
    }
    __builtin_amdgcn_s_barrier();
    __builtin_amdgcn_s_setprio(1);
#pragma unroll
    for (int mi = 0; mi < 8; ++mi)
#pragma unroll
      for (int ni = 0; ni < 4; ++ni)
        acc[mi][ni] = __builtin_amdgcn_mfma_f32_16x16x32_bf16(af[mi], bfr[ni], acc[mi][ni], 0, 0, 0);
    __builtin_amdgcn_s_setprio(0);
  }

  const int rj = (lane >> 4) << 2;
#pragma unroll
  for (int mi = 0; mi < 8; ++mi)
#pragma unroll
    for (int nf = 0; nf < 4; ++nf)
#pragma unroll
      for (int j = 0; j < 4; ++j) {
        int r = m0 + wm * 128 + mi * 16 + rj + j;
        int c = n0 + wn * 64 + nf * 16 + lr;
        float v = acc[mi][nf][j];
        if (MODE == 0) {
          v += bias[r];
          ((ushort*)Cout)[(size_t)r * N + c] = f2bf(v);
        } else {
          v += bias[c];
          ((float*)Cout)[(size_t)r * N + c] = v;
        }
      }
}

// ---------------- weight-fragment precompute ----------------
// Table values byte-identical to the verified conv's in-LDS frag build:
// wx[x] = (x in [15,270]) ? bf16(w[ch*256 + 270 - x]) : 0;
// frag[ch][kb][lane][jj] = wx[(lane&15) + kb*32 + 31 - 8*(lane>>4) - jj].
__global__ __launch_bounds__(256) void wfrag_prep(const float* __restrict__ w_a,
                                                  const float* __restrict__ w_b,
                                                  ushort* __restrict__ wfA,
                                                  ushort* __restrict__ wfB) {
  int gid = blockIdx.x * 256 + threadIdx.x;          // [0, 1024*9*64)
  int lane = gid & 63, kb = (gid >> 6) % 9, ch = gid / 576;
  int base = (lane & 15) + kb * 32 + 31 - 8 * (lane >> 4);
  ushort va[8], vb[8];
#pragma unroll
  for (int jj = 0; jj < 8; ++jj) {
    int i = base - jj;
    bool ok = (i >= 15) && (i <= 270);
    va[jj] = ok ? f2bf(w_a[ch * 256 + 270 - i]) : (ushort)0;
    vb[jj] = ok ? f2bf(w_b[ch * 256 + 270 - i]) : (ushort)0;
  }
  size_t off = ((size_t)(ch * 9 + kb) * 64 + lane) * 8;
#pragma unroll
  for (int jj = 0; jj < 8; ++jj) { wfA[off + jj] = va[jj]; wfB[off + jj] = vb[jj]; }
}

// ---------------- fused conv + gating + transposed write ----------------
// Block = (32 channel-pairs, 256-t chunk, b). Verified Toeplitz math with
// local window zs[r][i] = z[ch_r][T0-288+i] (i in [0,544), zero-padded head):
// B idx = 272 + 16*lidx - 32kb + 8g  (== verified formula at T0'=0).
// Outputs LDS-transposed and written to catT (bt, 2e) directly — removes the
// separate 134MB transpose kernel.
__global__ __launch_bounds__(512) void conv_gate_fused(
    const ushort* __restrict__ z, const ushort* __restrict__ wfA,
    const ushort* __restrict__ wfB, const float* __restrict__ b_a,
    const float* __restrict__ b_b, ushort* __restrict__ catT) {
  __shared__ __attribute__((aligned(16))) ushort zs[64 * 544];   // 68 KB
  __shared__ __attribute__((aligned(16))) ushort ot[64 * 260];   // 32.5 KB
  const int c0 = blockIdx.x * 32, T0 = blockIdx.y * 256, b = blockIdx.z;
  const int tid = threadIdx.x, lane = tid & 63, w = tid >> 6;
  const int h0 = (288 - T0) > 0 ? (288 - T0) : 0;   // zero-prefix elems
  // stage 64 z-row windows (rows 0..31 = a-ch c0+r; 32..63 = b-ch 1024+c0+r-32)
  for (int i = tid; i < 64 * 68; i += 512) {
    const int r = i / 68, c8 = (i % 68) * 8;
    const int ch = (r < 32) ? (c0 + r) : (1024 + c0 + (r - 32));
    ulonglong2 v = {0ull, 0ull};
    if (c8 >= h0)
      v = *(const ulonglong2*)&z[(size_t)ch * 16384 + b * 4096 + (T0 - 288 + c8)];
    *(ulonglong2*)&zs[r * 544 + c8] = v;
  }
  __syncthreads();
  const int lidx = lane & 15, g = lane >> 4;
  const int tloc = lidx * 16 + g * 4;
#pragma unroll
  for (int cp = 0; cp < 4; ++cp) {
    const int p = w * 4 + cp;           // pair 0..31
    const int ch = c0 + p;
    bf16x8 afA[9], afB[9];
#pragma unroll
    for (int kb = 0; kb < 9; ++kb) {
      size_t off = ((size_t)(ch * 9 + kb) * 64 + lane) * 8;
      afA[kb] = *(const bf16x8*)&wfA[off];
      afB[kb] = *(const bf16x8*)&wfB[off];
    }
    f32x4 accA = {}, accB = {};
#pragma unroll
    for (int kb = 0; kb < 9; ++kb) {
      const int idx = 272 + lidx * 16 - kb * 32 + g * 8;
      bf16x8 bza = *(const bf16x8*)&zs[p * 544 + idx];
      bf16x8 bzb = *(const bf16x8*)&zs[(32 + p) * 544 + idx];
      accA = __builtin_amdgcn_mfma_f32_16x16x32_bf16(afA[kb], bza, accA, 0, 0, 0);
      accB = __builtin_amdgcn_mfma_f32_16x16x32_bf16(afB[kb], bzb, accB, 0, 0, 0);
    }
    const float biasA = b_a[ch], biasB = b_b[ch];
    ushort4 oa, ob;
#pragma unroll
    for (int j = 0; j < 4; ++j) {
      float ca = accA[j] + biasA, cb = accB[j] + biasB;
      float sa = 1.f / (1.f + __expf(-ca));
      float sb = 1.f / (1.f + __expf(-cb));
      float va = ca * sb, vb = cb * sa;
      if (j == 0) { oa.x = f2bf(va); ob.x = f2bf(vb); }
      if (j == 1) { oa.y = f2bf(va); ob.y = f2bf(vb); }
      if (j == 2) { oa.z = f2bf(va); ob.z = f2bf(vb); }
      if (j == 3) { oa.w = f2bf(va); ob.w = f2bf(vb); }
    }
    *(ushort4*)&ot[p * 260 + tloc] = oa;           // 8B writes, lanes contiguous
    *(ushort4*)&ot[(32 + p) * 260 + tloc] = ob;
  }
  __syncthreads();
  // transposed global write: thread -> (t, half); 4 x 16B contiguous stores
  const int t = tid >> 1, half = tid & 1;
  ushort vb2[32];
#pragma unroll
  for (int j = 0; j < 32; ++j) vb2[j] = ot[(half * 32 + j) * 260 + t];
  ushort* gp = catT + (size_t)(b * 4096 + T0 + t) * 2048 + (half ? (1024 + c0) : c0);
#pragma unroll
  for (int q = 0; q < 4; ++q)
    *(ulonglong2*)&gp[q * 8] = *(const ulonglong2*)&vb2[q * 8];
}

extern "C" void kernel_launch(void* const* d_in, const int* in_sizes, int n_in,
                              void* d_out, int out_size, void* d_ws, size_t ws_size,
                              hipStream_t stream) {
  const float* x     = (const float*)d_in[0];
  const float* w_in  = (const float*)d_in[1];
  const float* b_in  = (const float*)d_in[2];
  const float* w_a   = (const float*)d_in[3];
  const float* b_a   = (const float*)d_in[4];
  const float* w_b   = (const float*)d_in[5];
  const float* b_b   = (const float*)d_in[6];
  const float* w_out = (const float*)d_in[7];
  const float* b_out = (const float*)d_in[8];

  uint8_t* ws = (uint8_t*)d_ws;
  ushort* x_bf     = (ushort*)(ws);                 // dead after GEMM1
  ushort* wfA      = (ushort*)(ws);                 // built after GEMM1
  ushort* wfB      = (ushort*)(ws + 9437184);
  ushort* w_in_bf  = (ushort*)(ws + 33554432);
  ushort* w_out_bf = (ushort*)(ws + 37748736);
  ushort* z        = (ushort*)(ws + 41943040);
  ushort* catT     = (ushort*)(ws + 109051904);

  cast_kernel<<<16384, 256, 0, stream>>>(x, x_bf, 4194304);
  cast_kernel<<<2048, 256, 0, stream>>>(w_in, w_in_bf, 524288);
  cast_kernel<<<2048, 256, 0, stream>>>(w_out, w_out_bf, 524288);

  // z(e,bt) = w_in(e,h) @ x(bt,h)^T + b_in[e]   M=2048,N=16384,K=1024
  gemm256<0, 1><<<dim3(512), 512, 0, stream>>>(w_in_bf, x_bf, b_in, z,
                                               2048, 16384, 1024, 8);
  // weight fragment tables (after GEMM1: reuses x_bf region)
  wfrag_prep<<<2304, 256, 0, stream>>>(w_a, w_b, wfA, wfB);
  // conv + gate + transpose -> catT(bt, 2e)
  conv_gate_fused<<<dim3(32, 16, 4), 512, 0, stream>>>(z, wfA, wfB, b_a, b_b, catT);
  // out(bt,h) = catT(bt,2e) @ w_out(h,2e)^T + b_out[h]  M=16384,N=1024,K=2048
  gemm256<1, 0><<<dim3(256), 512, 0, stream>>>(catT, w_out_bf, b_out, d_out,
                                               16384, 1024, 2048, 4);
}